// Round 7
// baseline (571.033 us; speedup 1.0000x reference)
//
#include <hip/hip_runtime.h>
#include <stdint.h>

#define M_DIM 8192
#define N_DIM 11008
#define K_DIM 4096

#define BM 128
#define BN 256
#define BK 64                    // i8: 64 B per row per tile
#define NT (K_DIM / BK)          // 64 K-tiles
#define GRID_M (M_DIM / BM)      // 64
#define GRID_N (N_DIM / BN)      // 43
#define NWG (GRID_M * GRID_N)    // 2752 (divisible by 8)

#define BUFA (BM * BK)           // 8192 B per A tile-buffer
#define BUFBB (BN * BK)          // 16384 B per B tile-buffer
// ring-3: LDS = 3*(BUFA+BUFBB) = 73728 B -> 2 blocks/CU (144 KiB <= 160)

typedef int i32x4 __attribute__((ext_vector_type(4)));

__device__ __forceinline__ void gload16(const int8_t* src, int8_t* dst) {
    __builtin_amdgcn_global_load_lds(
        (const __attribute__((address_space(1))) uint32_t*)src,
        (__attribute__((address_space(3))) uint32_t*)dst, 16, 0, 0);
}

// ---------- pre-pass 1: per-row (token) absmax quant of x -> i8 + inv scale ----------

__global__ __launch_bounds__(256) void quant_x_kernel(
    const float* __restrict__ x, int8_t* __restrict__ xq, float* __restrict__ sinv)
{
    const int wave = blockIdx.x * 4 + (threadIdx.x >> 6);
    const int lane = threadIdx.x & 63;
    const float* row = x + (size_t)wave * K_DIM;

    float4 v[16];
    float mx = 0.0f;
    #pragma unroll
    for (int j = 0; j < 16; ++j) {
        v[j] = *(const float4*)(row + (j * 64 + lane) * 4);
        mx = fmaxf(mx, fmaxf(fmaxf(fabsf(v[j].x), fabsf(v[j].y)),
                             fmaxf(fabsf(v[j].z), fabsf(v[j].w))));
    }
    #pragma unroll
    for (int off = 32; off > 0; off >>= 1)
        mx = fmaxf(mx, __shfl_xor(mx, off));
    if (mx < 1e-30f) mx = 1e-30f;
    const float s = 127.0f / mx;

    int8_t* orow = xq + (size_t)wave * K_DIM;
    #pragma unroll
    for (int j = 0; j < 16; ++j) {
        int a = (int)__builtin_rintf(v[j].x * s);
        int b = (int)__builtin_rintf(v[j].y * s);
        int c = (int)__builtin_rintf(v[j].z * s);
        int d = (int)__builtin_rintf(v[j].w * s);
        uint32_t p = (uint32_t)(a & 0xFF) | ((uint32_t)(b & 0xFF) << 8) |
                     ((uint32_t)(c & 0xFF) << 16) | ((uint32_t)(d & 0xFF) << 24);
        *(uint32_t*)(orow + (j * 64 + lane) * 4) = p;
    }
    if (lane == 0) sinv[wave] = mx / 127.0f;
}

// ---------- pre-pass 2: f32 w -> sign(w) in i8 (exact {-1,0,+1}) ----------

__global__ __launch_bounds__(256) void sign_w_kernel(
    const float* __restrict__ w, int8_t* __restrict__ wq, long long n16)
{
    long long i = (long long)blockIdx.x * blockDim.x + threadIdx.x;
    const long long stride = (long long)gridDim.x * blockDim.x;
    for (; i < n16; i += stride) {
        const float* src = w + i * 16;
        uint32_t pk[4];
        #pragma unroll
        for (int q = 0; q < 4; ++q) {
            float4 f = *(const float4*)(src + q * 4);
            int a = (f.x > 0.f) ? 1 : ((f.x < 0.f) ? -1 : 0);
            int b = (f.y > 0.f) ? 1 : ((f.y < 0.f) ? -1 : 0);
            int c = (f.z > 0.f) ? 1 : ((f.z < 0.f) ? -1 : 0);
            int d = (f.w > 0.f) ? 1 : ((f.w < 0.f) ? -1 : 0);
            pk[q] = (uint32_t)(a & 0xFF) | ((uint32_t)(b & 0xFF) << 8) |
                    ((uint32_t)(c & 0xFF) << 16) | ((uint32_t)(d & 0xFF) << 24);
        }
        *(i32x4*)(wq + i * 16) = (i32x4){(int)pk[0], (int)pk[1], (int)pk[2], (int)pk[3]};
    }
}

// ---------- main GEMM (i8): 128x256 tile, BK=64, 8 waves, RING-3 LDS (72 KiB)
// -> 2 INDEPENDENT blocks/CU (launch_bounds(512,4), 128-reg cap; acc=64 regs,
// total ~121 -> no spill, unlike r5's acc=128@cap128).
// Rationale (r6 post-mortem): one barrier-locked block serializes the DS-read
// stretch (1152 cy) and MFMA stretch (1307 cy) per tile = 2750 cy measured.
// Two independent blocks per CU co-schedule: one MFMAs while the other does
// DS/staging (m114) -> per-CU throughput -> max(DS, MFMA) instead of sum.
//
// Ring-3 schedule per block, phase(t) [slot b = t % 3]:
//   8 ds_read_b128 frags(t) from buf[b]
//   lgkmcnt(0); s_barrier                 // all waves' reads of buf[b] done
//   stage(t+3) -> buf[b]                  // WAR-safe; 3 gload_lds/thread
//   MFMA x16
//   trailing: t<=NT-4: vmcnt(6)  (in-flight {t+1,t+2,t+3}x3, drains t+1)
//             t==NT-3: vmcnt(3)  (in-flight {t+1,t+2}x3, drains t+1)
//             else:    vmcnt(0)
//   s_barrier
// RAW: stage(t) drained by phase(t-1)'s trailing wait + barrier (all waves).
// Slack for stage(t+1): ~2.5 phases.
//
// LDS swizzle (r6-verified): read slot = l4 ^ ((l15>>1)&3); staged global src
// slot = (tid&3) ^ ((tid>>3)&3). Row-dependence check: fragment row =
// {wm,wn}*16 + l15 + {g*32|h*64} -> (row>>1)&3 == (l15>>1)&3 for all g,h. OK.

__global__ __launch_bounds__(512, 4) void ternary_gemm_i8(
    const int8_t* __restrict__ A, const int8_t* __restrict__ B,
    const float* __restrict__ bias, const float* __restrict__ sinv,
    float* __restrict__ out)
{
    extern __shared__ int8_t lds[];
    int8_t* As = lds;                  // [3][BUFA]
    int8_t* Bs = lds + 3 * BUFA;       // [3][BUFBB]

    const int tid  = threadIdx.x;
    const int lane = tid & 63;
    const int wid  = tid >> 6;        // 0..7
    const int wm   = wid >> 2;        // 0..1  (M halves of 64 rows... 2x64=128)
    const int wn   = wid & 3;         // 0..3  (N quarters of 64 cols)
    const int l15  = lane & 15;
    const int l4   = lane >> 4;       // 0..3

    // T1: bijective XCD swizzle (NWG % 8 == 0), bn-minor for x-panel L2 reuse
    const int bid = blockIdx.x;
    const int swz = (bid & 7) * (NWG / 8) + (bid >> 3);
    const int bm  = swz / GRID_N;
    const int bn  = swz % GRID_N;
    const long brow = (long)bm * BM;
    const long bcol = (long)bn * BN;

    // ---- staging addressing: inst covers 128 rows; row = tid>>2, slot tid&3;
    // LDS dest linear (byte = tid*16); global src slot inverse-swizzled ----
    const int rowt = tid >> 2;                        // 0..127
    const int ssrc = (tid & 3) ^ ((tid >> 3) & 3);
    const int8_t* pA = A + (size_t)(brow + rowt) * K_DIM + ssrc * 16;
    const int8_t* pB = B + (size_t)(bcol + rowt) * K_DIM + ssrc * 16;

    auto stageAB = [&](int t, int bslot) {
        gload16(pA + (size_t)t * BK, As + bslot * BUFA + wid * 1024 + (lane << 4));
        #pragma unroll
        for (int r = 0; r < 2; ++r)
            gload16(pB + (size_t)r * 128 * K_DIM + (size_t)t * BK,
                    Bs + bslot * BUFBB + r * 8192 + wid * 1024 + (lane << 4));
    };

    // ---- fragment read addressing (swizzled slot, const per thread) ----
    const int slot = l4 ^ ((l15 >> 1) & 3);
    const int aOff = (wm * 16 + l15) * 64 + slot * 16;   // + g*2048 (g*32 rows)
    const int bOff = (wn * 16 + l15) * 64 + slot * 16;   // + h*4096 (h*64 rows)

    i32x4 acc[4][4];
    #pragma unroll
    for (int g = 0; g < 4; ++g)
        #pragma unroll
        for (int h = 0; h < 4; ++h) acc[g][h] = (i32x4){0, 0, 0, 0};

    // ---- prologue: stage tiles 0,1,2 (9 insts); drain tile 0; barrier ----
    stageAB(0, 0);
    stageAB(1, 1);
    stageAB(2, 2);
    asm volatile("s_waitcnt vmcnt(6)" ::: "memory");
    __builtin_amdgcn_s_barrier();
    __builtin_amdgcn_sched_barrier(0);

    int bcur = 0;
    for (int t = 0; t < NT; ++t) {
        const int b = bcur;

        i32x4 ar[4], br[4];
        #pragma unroll
        for (int g = 0; g < 4; ++g)
            ar[g] = *(const i32x4*)(As + b * BUFA + g * 2048 + aOff);
        #pragma unroll
        for (int h = 0; h < 4; ++h)
            br[h] = *(const i32x4*)(Bs + b * BUFBB + h * 4096 + bOff);
        __builtin_amdgcn_sched_barrier(0);
        asm volatile("s_waitcnt lgkmcnt(0)" ::: "memory");
        __builtin_amdgcn_s_barrier();            // all waves' reads of buf[b] done
        __builtin_amdgcn_sched_barrier(0);

        if (t + 3 < NT) stageAB(t + 3, b);       // -> same slot, WAR-safe
        __builtin_amdgcn_sched_barrier(0);

        __builtin_amdgcn_s_setprio(1);
        #pragma unroll
        for (int g = 0; g < 4; ++g)
            #pragma unroll
            for (int h = 0; h < 4; ++h)
                acc[g][h] = __builtin_amdgcn_mfma_i32_16x16x64_i8(ar[g], br[h], acc[g][h], 0, 0, 0);
        __builtin_amdgcn_s_setprio(0);
        __builtin_amdgcn_sched_barrier(0);

        if (t <= NT - 4)      { asm volatile("s_waitcnt vmcnt(6)" ::: "memory"); }
        else if (t == NT - 3) { asm volatile("s_waitcnt vmcnt(3)" ::: "memory"); }
        else                  { asm volatile("s_waitcnt vmcnt(0)" ::: "memory"); }
        __builtin_amdgcn_s_barrier();
        __builtin_amdgcn_sched_barrier(0);

        bcur = (bcur == 2) ? 0 : bcur + 1;
    }

    // ---- epilogue: out = acc * sinv[row] + bias[col] ----
    // C/D layout (dtype-independent, m121-128): col=lane&15, row=(lane>>4)*4+reg
    int   cols[4];
    float bv[4];
    #pragma unroll
    for (int h = 0; h < 4; ++h) {
        cols[h] = (int)bcol + h * 64 + wn * 16 + l15;
        bv[h] = bias[cols[h]];
    }
    #pragma unroll
    for (int g = 0; g < 4; ++g) {
        const size_t row0 = (size_t)brow + g * 32 + wm * 16 + l4 * 4;
        float s0 = sinv[row0], s1 = sinv[row0 + 1], s2 = sinv[row0 + 2], s3 = sinv[row0 + 3];
        #pragma unroll
        for (int h = 0; h < 4; ++h) {
            out[(row0 + 0) * N_DIM + cols[h]] = (float)acc[g][h][0] * s0 + bv[h];
            out[(row0 + 1) * N_DIM + cols[h]] = (float)acc[g][h][1] * s1 + bv[h];
            out[(row0 + 2) * N_DIM + cols[h]] = (float)acc[g][h][2] * s2 + bv[h];
            out[(row0 + 3) * N_DIM + cols[h]] = (float)acc[g][h][3] * s3 + bv[h];
        }
    }
}

// ---------- fallback (only if workspace too small): correct but slow ----------

__global__ void naive_kernel(const float* __restrict__ x, const float* __restrict__ w,
                             const float* __restrict__ bias, float* __restrict__ out) {
    long long o = (long long)blockIdx.x * blockDim.x + threadIdx.x;
    if (o >= (long long)M_DIM * N_DIM) return;
    int row = (int)(o / N_DIM), col = (int)(o % N_DIM);
    float s = 0.0f;
    const float* xr = x + (size_t)row * K_DIM;
    const float* wr = w + (size_t)col * K_DIM;
    for (int k = 0; k < K_DIM; ++k) {
        float wv = wr[k];
        s += (wv > 0.0f) ? xr[k] : ((wv < 0.0f) ? -xr[k] : 0.0f);
    }
    out[o] = s + bias[col];
}

// ---------- launch ----------

extern "C" void kernel_launch(void* const* d_in, const int* in_sizes, int n_in,
                              void* d_out, int out_size, void* d_ws, size_t ws_size,
                              hipStream_t stream) {
    const float* x    = (const float*)d_in[0];
    const float* w    = (const float*)d_in[1];
    const float* bias = (const float*)d_in[2];
    float* out        = (float*)d_out;

    const size_t xq_bytes = (size_t)M_DIM * K_DIM;        // 33.6 MB
    const size_t wq_bytes = (size_t)N_DIM * K_DIM;        // 45.1 MB
    const size_t si_bytes = (size_t)M_DIM * sizeof(float);

    if (ws_size >= xq_bytes + wq_bytes + si_bytes) {
        int8_t* xq   = (int8_t*)d_ws;
        int8_t* wq   = (int8_t*)((char*)d_ws + xq_bytes);
        float*  sinv = (float*)((char*)d_ws + xq_bytes + wq_bytes);

        quant_x_kernel<<<M_DIM / 4, 256, 0, stream>>>(x, xq, sinv);
        const long long n16 = ((long long)N_DIM * K_DIM) / 16;
        sign_w_kernel<<<2048, 256, 0, stream>>>(w, wq, n16);

        const int lds_bytes = 3 * (BUFA + BUFBB);   // 73728
        hipFuncSetAttribute(reinterpret_cast<const void*>(ternary_gemm_i8),
                            hipFuncAttributeMaxDynamicSharedMemorySize, lds_bytes);
        ternary_gemm_i8<<<NWG, 512, lds_bytes, stream>>>(xq, wq, bias, sinv, out);
    } else {
        const long long total = (long long)M_DIM * N_DIM;
        naive_kernel<<<(int)((total + 255) / 256), 256, 0, stream>>>(x, w, bias, out);
    }
}

// Round 8
// 481.856 us; speedup vs baseline: 1.1851x; 1.1851x over previous
//
#include <hip/hip_runtime.h>
#include <stdint.h>

#define M_DIM 8192
#define N_DIM 11008
#define K_DIM 4096

#define BM 256
#define BN 256
#define BK 64                    // i8: 64 B per row per tile
#define NT (K_DIM / BK)          // 64 K-tiles
#define GRID_M (M_DIM / BM)      // 32
#define GRID_N (N_DIM / BN)      // 43
#define NWG (GRID_M * GRID_N)    // 1376 (divisible by 8)

#define BUF (BM * BK)            // 16384 B per tile-buffer per matrix
#define NRING 5                  // ring-5: LDS = 5*2*16384 = 163840 B (full 160 KiB)

typedef int i32x4 __attribute__((ext_vector_type(4)));

__device__ __forceinline__ void gload16(const int8_t* src, int8_t* dst) {
    __builtin_amdgcn_global_load_lds(
        (const __attribute__((address_space(1))) uint32_t*)src,
        (__attribute__((address_space(3))) uint32_t*)dst, 16, 0, 0);
}

// ---------- pre-pass 1: per-row (token) absmax quant of x -> i8 + inv scale ----------

__global__ __launch_bounds__(256) void quant_x_kernel(
    const float* __restrict__ x, int8_t* __restrict__ xq, float* __restrict__ sinv)
{
    const int wave = blockIdx.x * 4 + (threadIdx.x >> 6);
    const int lane = threadIdx.x & 63;
    const float* row = x + (size_t)wave * K_DIM;

    float4 v[16];
    float mx = 0.0f;
    #pragma unroll
    for (int j = 0; j < 16; ++j) {
        v[j] = *(const float4*)(row + (j * 64 + lane) * 4);
        mx = fmaxf(mx, fmaxf(fmaxf(fabsf(v[j].x), fabsf(v[j].y)),
                             fmaxf(fabsf(v[j].z), fabsf(v[j].w))));
    }
    #pragma unroll
    for (int off = 32; off > 0; off >>= 1)
        mx = fmaxf(mx, __shfl_xor(mx, off));
    if (mx < 1e-30f) mx = 1e-30f;
    const float s = 127.0f / mx;

    int8_t* orow = xq + (size_t)wave * K_DIM;
    #pragma unroll
    for (int j = 0; j < 16; ++j) {
        int a = (int)__builtin_rintf(v[j].x * s);
        int b = (int)__builtin_rintf(v[j].y * s);
        int c = (int)__builtin_rintf(v[j].z * s);
        int d = (int)__builtin_rintf(v[j].w * s);
        uint32_t p = (uint32_t)(a & 0xFF) | ((uint32_t)(b & 0xFF) << 8) |
                     ((uint32_t)(c & 0xFF) << 16) | ((uint32_t)(d & 0xFF) << 24);
        *(uint32_t*)(orow + (j * 64 + lane) * 4) = p;
    }
    if (lane == 0) sinv[wave] = mx / 127.0f;
}

// ---------- pre-pass 2: f32 w -> sign(w) in i8 (exact {-1,0,+1}) ----------

__global__ __launch_bounds__(256) void sign_w_kernel(
    const float* __restrict__ w, int8_t* __restrict__ wq, long long n16)
{
    long long i = (long long)blockIdx.x * blockDim.x + threadIdx.x;
    const long long stride = (long long)gridDim.x * blockDim.x;
    for (; i < n16; i += stride) {
        const float* src = w + i * 16;
        uint32_t pk[4];
        #pragma unroll
        for (int q = 0; q < 4; ++q) {
            float4 f = *(const float4*)(src + q * 4);
            int a = (f.x > 0.f) ? 1 : ((f.x < 0.f) ? -1 : 0);
            int b = (f.y > 0.f) ? 1 : ((f.y < 0.f) ? -1 : 0);
            int c = (f.z > 0.f) ? 1 : ((f.z < 0.f) ? -1 : 0);
            int d = (f.w > 0.f) ? 1 : ((f.w < 0.f) ? -1 : 0);
            pk[q] = (uint32_t)(a & 0xFF) | ((uint32_t)(b & 0xFF) << 8) |
                    ((uint32_t)(c & 0xFF) << 16) | ((uint32_t)(d & 0xFF) << 24);
        }
        *(i32x4*)(wq + i * 16) = (i32x4){(int)pk[0], (int)pk[1], (int)pk[2], (int)pk[3]};
    }
}

// ---------- main GEMM (i8): 256x256, BK=64, 8 waves, RING-5 LDS (160 KiB),
// cross-tile fragment double-buffering: ds_reads for tile t+1 issue BEFORE the
// MFMAs of tile t and drain UNDER them (lgkmcnt(12) leaves them in flight).
// r6 post-mortem: i8 DS leg (1152 cy/CU/tile) < MFMA leg (1307 cy) -> overlap
// makes the tile MFMA-bound instead of serial DS+MFMA (2750 cy measured).
//
// body(t)  [cur frag set holds tile t; slot(x) = x % 5]:
//   1. issue 12 ds_reads frags(t+1) from slot(t+1) -> next frag set
//      [RAW: stage(t+1) drained at body(t-1) step 5 + barrier]
//   2. lgkmcnt(12)  -> frags(t) complete per-wave (newest 12 = reads(t+1) stay)
//   3. stage(t+4) -> slot(t+4) == slot(t-1)
//      [WAR: all waves' reads(t-1) completed at their body(t-1) step 2, and
//       body(t-1)'s end barrier orders that before this write]
//   4. MFMA x32 on cur set (reads t+1 drain under this)
//   5. vmcnt ladder: t<=NT-5: vmcnt(8) (outstanding {t+2,t+3,t+4}x4 -> drains
//      stage(t+2)); t==NT-4: vmcnt(4); else vmcnt(0). THEN s_barrier.
//      [stage(t+2) slack: issued body(t-2), drained body(t) ~ 2.6 tiles]
// Frag sets are two NAMED register arrays alternated by a 2-unrolled loop
// (rule #20: no runtime-indexed frag arrays).

__global__ __launch_bounds__(512, 2) void ternary_gemm_i8(
    const int8_t* __restrict__ A, const int8_t* __restrict__ B,
    const float* __restrict__ bias, const float* __restrict__ sinv,
    float* __restrict__ out)
{
    extern __shared__ int8_t lds[];
    int8_t* As = lds;                   // [NRING][BUF]
    int8_t* Bs = lds + NRING * BUF;     // [NRING][BUF]

    const int tid  = threadIdx.x;
    const int lane = tid & 63;
    const int wid  = tid >> 6;        // 0..7
    const int wm   = wid >> 2;        // 0..1
    const int wn   = wid & 3;         // 0..3
    const int l15  = lane & 15;
    const int l4   = lane >> 4;       // 0..3

    // T1: bijective XCD swizzle (NWG % 8 == 0), bn-minor for A-panel L2 reuse
    const int bid = blockIdx.x;
    const int swz = (bid & 7) * (NWG / 8) + (bid >> 3);
    const int bm  = swz / GRID_N;
    const int bn  = swz % GRID_N;
    const long brow = (long)bm * BM;
    const long bcol = (long)bn * BN;

    // ---- staging addressing (r6-verified): inst r covers rows r*128+(tid>>2),
    // 16B-slot tid&3; LDS dest linear (byte = r*8192 + tid*16); global src
    // slot inverse-swizzled: (tid&3) ^ ((tid>>3)&3) ----
    const int rowt = tid >> 2;                        // 0..127
    const int ssrc = (tid & 3) ^ ((tid >> 3) & 3);
    const int8_t* pA = A + (size_t)(brow + rowt) * K_DIM + ssrc * 16;
    const int8_t* pB = B + (size_t)(bcol + rowt) * K_DIM + ssrc * 16;

    auto stageAB = [&](int t, int bslot) {
        #pragma unroll
        for (int r = 0; r < 2; ++r)
            gload16(pA + (size_t)r * 128 * K_DIM + (size_t)t * BK,
                    As + bslot * BUF + r * 8192 + wid * 1024 + (lane << 4));
        #pragma unroll
        for (int r = 0; r < 2; ++r)
            gload16(pB + (size_t)r * 128 * K_DIM + (size_t)t * BK,
                    Bs + bslot * BUF + r * 8192 + wid * 1024 + (lane << 4));
    };

    // ---- fragment read addressing (r6-verified swizzle) ----
    const int slot = l4 ^ ((l15 >> 1) & 3);
    const int aOff = (wm * 16 + l15) * 64 + slot * 16;   // + m*2048
    const int bOff = (wn * 16 + l15) * 64 + slot * 16;   // + n*4096

    i32x4 acc[8][4];
    #pragma unroll
    for (int m = 0; m < 8; ++m)
        #pragma unroll
        for (int n = 0; n < 4; ++n) acc[m][n] = (i32x4){0, 0, 0, 0};

    i32x4 arA[8], brA[4], arB[8], brB[4];

    auto readFrags = [&](int t, i32x4 (&ar)[8], i32x4 (&br)[4]) {
        const int s = t % NRING;
        const int8_t* Ab = As + s * BUF;
        const int8_t* Bb = Bs + s * BUF;
        #pragma unroll
        for (int m = 0; m < 8; ++m) ar[m] = *(const i32x4*)(Ab + m * 2048 + aOff);
        #pragma unroll
        for (int n = 0; n < 4; ++n) br[n] = *(const i32x4*)(Bb + n * 4096 + bOff);
    };

    // ---- prologue: stage tiles 0..3 (16 insts); drain 0,1 (vmcnt(8)); barrier;
    // preload frags(0) -> set A ----
    stageAB(0, 0); stageAB(1, 1); stageAB(2, 2); stageAB(3, 3);
    asm volatile("s_waitcnt vmcnt(8)" ::: "memory");
    __builtin_amdgcn_s_barrier();
    __builtin_amdgcn_sched_barrier(0);
    readFrags(0, arA, brA);
    __builtin_amdgcn_sched_barrier(0);

    auto body = [&](int t, i32x4 (&arc)[8], i32x4 (&brc)[4],
                           i32x4 (&arn)[8], i32x4 (&brn)[4]) {
        // 1. reads(t+1) -> next set (slot drained at body(t-1) step 5 + barrier)
        if (t + 1 < NT) {
            readFrags(t + 1, arn, brn);
            __builtin_amdgcn_sched_barrier(0);
            asm volatile("s_waitcnt lgkmcnt(12)" ::: "memory");  // frags(t) ready
        } else {
            asm volatile("s_waitcnt lgkmcnt(0)" ::: "memory");
        }
        __builtin_amdgcn_sched_barrier(0);

        // 3. stage(t+4) into slot(t-1) (WAR certified by body(t-1) barrier)
        if (t + 4 < NT) stageAB(t + 4, (t + 4) % NRING);
        __builtin_amdgcn_sched_barrier(0);

        // 4. MFMA on cur set; reads(t+1) drain underneath
        __builtin_amdgcn_s_setprio(1);
        #pragma unroll
        for (int m = 0; m < 8; ++m)
            #pragma unroll
            for (int n = 0; n < 4; ++n)
                acc[m][n] = __builtin_amdgcn_mfma_i32_16x16x64_i8(arc[m], brc[n], acc[m][n], 0, 0, 0);
        __builtin_amdgcn_s_setprio(0);
        __builtin_amdgcn_sched_barrier(0);

        // 5. counted vmcnt ladder (never 0 until tail), then barrier
        if (t <= NT - 5)      { asm volatile("s_waitcnt vmcnt(8)" ::: "memory"); }
        else if (t == NT - 4) { asm volatile("s_waitcnt vmcnt(4)" ::: "memory"); }
        else                  { asm volatile("s_waitcnt vmcnt(0)" ::: "memory"); }
        __builtin_amdgcn_s_barrier();
        __builtin_amdgcn_sched_barrier(0);
    };

    for (int t = 0; t < NT; t += 2) {
        body(t,     arA, brA, arB, brB);
        body(t + 1, arB, brB, arA, brA);
    }

    // ---- epilogue: out = acc * sinv[row] + bias[col] ----
    // C/D layout (dtype-independent, m121-128): col=lane&15, row=(lane>>4)*4+reg
    int   cols[4];
    float bv[4];
    #pragma unroll
    for (int n = 0; n < 4; ++n) {
        cols[n] = (int)bcol + n * 64 + wn * 16 + l15;
        bv[n] = bias[cols[n]];
    }
    #pragma unroll
    for (int m = 0; m < 8; ++m) {
        const size_t row0 = (size_t)brow + m * 32 + wm * 16 + l4 * 4;
        float s0 = sinv[row0], s1 = sinv[row0 + 1], s2 = sinv[row0 + 2], s3 = sinv[row0 + 3];
        #pragma unroll
        for (int n = 0; n < 4; ++n) {
            out[(row0 + 0) * N_DIM + cols[n]] = (float)acc[m][n][0] * s0 + bv[n];
            out[(row0 + 1) * N_DIM + cols[n]] = (float)acc[m][n][1] * s1 + bv[n];
            out[(row0 + 2) * N_DIM + cols[n]] = (float)acc[m][n][2] * s2 + bv[n];
            out[(row0 + 3) * N_DIM + cols[n]] = (float)acc[m][n][3] * s3 + bv[n];
        }
    }
}

// ---------- fallback (only if workspace too small): correct but slow ----------

__global__ void naive_kernel(const float* __restrict__ x, const float* __restrict__ w,
                             const float* __restrict__ bias, float* __restrict__ out) {
    long long o = (long long)blockIdx.x * blockDim.x + threadIdx.x;
    if (o >= (long long)M_DIM * N_DIM) return;
    int row = (int)(o / N_DIM), col = (int)(o % N_DIM);
    float s = 0.0f;
    const float* xr = x + (size_t)row * K_DIM;
    const float* wr = w + (size_t)col * K_DIM;
    for (int k = 0; k < K_DIM; ++k) {
        float wv = wr[k];
        s += (wv > 0.0f) ? xr[k] : ((wv < 0.0f) ? -xr[k] : 0.0f);
    }
    out[o] = s + bias[col];
}

// ---------- launch ----------

extern "C" void kernel_launch(void* const* d_in, const int* in_sizes, int n_in,
                              void* d_out, int out_size, void* d_ws, size_t ws_size,
                              hipStream_t stream) {
    const float* x    = (const float*)d_in[0];
    const float* w    = (const float*)d_in[1];
    const float* bias = (const float*)d_in[2];
    float* out        = (float*)d_out;

    const size_t xq_bytes = (size_t)M_DIM * K_DIM;        // 33.6 MB
    const size_t wq_bytes = (size_t)N_DIM * K_DIM;        // 45.1 MB
    const size_t si_bytes = (size_t)M_DIM * sizeof(float);

    if (ws_size >= xq_bytes + wq_bytes + si_bytes) {
        int8_t* xq   = (int8_t*)d_ws;
        int8_t* wq   = (int8_t*)((char*)d_ws + xq_bytes);
        float*  sinv = (float*)((char*)d_ws + xq_bytes + wq_bytes);

        quant_x_kernel<<<M_DIM / 4, 256, 0, stream>>>(x, xq, sinv);
        const long long n16 = ((long long)N_DIM * K_DIM) / 16;
        sign_w_kernel<<<2048, 256, 0, stream>>>(w, wq, n16);

        const int lds_bytes = NRING * 2 * BUF;   // 163840
        hipFuncSetAttribute(reinterpret_cast<const void*>(ternary_gemm_i8),
                            hipFuncAttributeMaxDynamicSharedMemorySize, lds_bytes);
        ternary_gemm_i8<<<NWG, 512, lds_bytes, stream>>>(xq, wq, bias, sinv, out);
    } else {
        const long long total = (long long)M_DIM * N_DIM;
        naive_kernel<<<(int)((total + 255) / 256), 256, 0, stream>>>(x, w, bias, out);
    }
}

// Round 9
// 479.399 us; speedup vs baseline: 1.1911x; 1.0051x over previous
//
#include <hip/hip_runtime.h>
#include <stdint.h>

#define M_DIM 8192
#define N_DIM 11008
#define K_DIM 4096

#define BM 256
#define BN 256
#define BK 64                    // i8: 64 B per row per tile
#define NT (K_DIM / BK)          // 64 K-tiles
#define GRID_M (M_DIM / BM)      // 32
#define GRID_N (N_DIM / BN)      // 43
#define NWG (GRID_M * GRID_N)    // 1376 (divisible by 8)

#define BUF (BM * BK)            // 16384 B per tile-buffer per matrix
#define NRING 5                  // ring-5: LDS = 5*2*16384 = 163840 B (160 KiB)

typedef int i32x4 __attribute__((ext_vector_type(4)));

__device__ __forceinline__ void gload16(const int8_t* src, int8_t* dst) {
    __builtin_amdgcn_global_load_lds(
        (const __attribute__((address_space(1))) uint32_t*)src,
        (__attribute__((address_space(3))) uint32_t*)dst, 16, 0, 0);
}

// ---------- pre-pass 1: per-row (token) absmax quant of x -> i8 + inv scale ----------

__global__ __launch_bounds__(256) void quant_x_kernel(
    const float* __restrict__ x, int8_t* __restrict__ xq, float* __restrict__ sinv)
{
    const int wave = blockIdx.x * 4 + (threadIdx.x >> 6);
    const int lane = threadIdx.x & 63;
    const float* row = x + (size_t)wave * K_DIM;

    float4 v[16];
    float mx = 0.0f;
    #pragma unroll
    for (int j = 0; j < 16; ++j) {
        v[j] = *(const float4*)(row + (j * 64 + lane) * 4);
        mx = fmaxf(mx, fmaxf(fmaxf(fabsf(v[j].x), fabsf(v[j].y)),
                             fmaxf(fabsf(v[j].z), fabsf(v[j].w))));
    }
    #pragma unroll
    for (int off = 32; off > 0; off >>= 1)
        mx = fmaxf(mx, __shfl_xor(mx, off));
    if (mx < 1e-30f) mx = 1e-30f;
    const float s = 127.0f / mx;

    int8_t* orow = xq + (size_t)wave * K_DIM;
    #pragma unroll
    for (int j = 0; j < 16; ++j) {
        int a = (int)__builtin_rintf(v[j].x * s);
        int b = (int)__builtin_rintf(v[j].y * s);
        int c = (int)__builtin_rintf(v[j].z * s);
        int d = (int)__builtin_rintf(v[j].w * s);
        uint32_t p = (uint32_t)(a & 0xFF) | ((uint32_t)(b & 0xFF) << 8) |
                     ((uint32_t)(c & 0xFF) << 16) | ((uint32_t)(d & 0xFF) << 24);
        *(uint32_t*)(orow + (j * 64 + lane) * 4) = p;
    }
    if (lane == 0) sinv[wave] = mx / 127.0f;
}

// ---------- pre-pass 2: f32 w -> sign(w) in i8 (exact {-1,0,+1}) ----------

__global__ __launch_bounds__(256) void sign_w_kernel(
    const float* __restrict__ w, int8_t* __restrict__ wq, long long n16)
{
    long long i = (long long)blockIdx.x * blockDim.x + threadIdx.x;
    const long long stride = (long long)gridDim.x * blockDim.x;
    for (; i < n16; i += stride) {
        const float* src = w + i * 16;
        uint32_t pk[4];
        #pragma unroll
        for (int q = 0; q < 4; ++q) {
            float4 f = *(const float4*)(src + q * 4);
            int a = (f.x > 0.f) ? 1 : ((f.x < 0.f) ? -1 : 0);
            int b = (f.y > 0.f) ? 1 : ((f.y < 0.f) ? -1 : 0);
            int c = (f.z > 0.f) ? 1 : ((f.z < 0.f) ? -1 : 0);
            int d = (f.w > 0.f) ? 1 : ((f.w < 0.f) ? -1 : 0);
            pk[q] = (uint32_t)(a & 0xFF) | ((uint32_t)(b & 0xFF) << 8) |
                    ((uint32_t)(c & 0xFF) << 16) | ((uint32_t)(d & 0xFF) << 24);
        }
        *(i32x4*)(wq + i * 16) = (i32x4){(int)pk[0], (int)pk[1], (int)pk[2], (int)pk[3]};
    }
}

// ---------- main GEMM (i8): 256x256, BK=64, 8 waves, RING-5 LDS (160 KiB).
// r8 post-mortem: sched_barrier(0) fences between the 12 ds_reads and the 32
// MFMAs FORBADE the compiler from interleaving issue -> DS issue stretch
// (~1150 cy) serialized with MFMA stretch (~1300 cy) = 2590 cy/tile measured
// (m141 lesson). This version DE-PINS the body: no fences between reads /
// stage / MFMA; hipcc interleaves MFMAs among ds_read issues with fine-grained
// lgkmcnt (m97 behavior). Correctness:
//  - MFMA(t) operands are register results of reads(t) (plain C++ loads,
//    issued last tile) -> compiler auto-waits. No rule-18 hazard (that needs
//    manually-managed asm ds_reads).
//  - Tile boundary block: lgkmcnt(12) [drains all but the 12 reads(t+1) ->
//    formal WAR guard: every wave's reads older than t+1 done before barrier],
//    sched_barrier, vmcnt ladder (8/4/0 -> stage(t+2) landed for next tile,
//    never 0 until tail), s_barrier, sched_barrier.
//  - stage(t+4) -> slot(t-1): all waves' reads(t-1) drained at body(t-1)
//    boundary lgkm+barrier; write lands >=HBM-latency after issue. Ring-5
//    gives ~2.5 tiles of RAW slack for each stage.

__global__ __launch_bounds__(512, 2) void ternary_gemm_i8(
    const int8_t* __restrict__ A, const int8_t* __restrict__ B,
    const float* __restrict__ bias, const float* __restrict__ sinv,
    float* __restrict__ out)
{
    extern __shared__ int8_t lds[];
    int8_t* As = lds;                   // [NRING][BUF]
    int8_t* Bs = lds + NRING * BUF;     // [NRING][BUF]

    const int tid  = threadIdx.x;
    const int lane = tid & 63;
    const int wid  = tid >> 6;        // 0..7
    const int wm   = wid >> 2;        // 0..1
    const int wn   = wid & 3;         // 0..3
    const int l15  = lane & 15;
    const int l4   = lane >> 4;       // 0..3

    // T1: bijective XCD swizzle (NWG % 8 == 0), bn-minor for A-panel L2 reuse
    const int bid = blockIdx.x;
    const int swz = (bid & 7) * (NWG / 8) + (bid >> 3);
    const int bm  = swz / GRID_N;
    const int bn  = swz % GRID_N;
    const long brow = (long)bm * BM;
    const long bcol = (long)bn * BN;

    // ---- staging addressing (r6-verified): inst r covers rows r*128+(tid>>2),
    // 16B-slot tid&3; LDS dest linear (byte = r*8192 + tid*16); global src
    // slot inverse-swizzled: (tid&3) ^ ((tid>>3)&3) ----
    const int rowt = tid >> 2;                        // 0..127
    const int ssrc = (tid & 3) ^ ((tid >> 3) & 3);
    const int8_t* pA = A + (size_t)(brow + rowt) * K_DIM + ssrc * 16;
    const int8_t* pB = B + (size_t)(bcol + rowt) * K_DIM + ssrc * 16;

    auto stageAB = [&](int t, int bslot) {
        #pragma unroll
        for (int r = 0; r < 2; ++r)
            gload16(pA + (size_t)r * 128 * K_DIM + (size_t)t * BK,
                    As + bslot * BUF + r * 8192 + wid * 1024 + (lane << 4));
        #pragma unroll
        for (int r = 0; r < 2; ++r)
            gload16(pB + (size_t)r * 128 * K_DIM + (size_t)t * BK,
                    Bs + bslot * BUF + r * 8192 + wid * 1024 + (lane << 4));
    };

    // ---- fragment read addressing (r6-verified swizzle) ----
    const int slot = l4 ^ ((l15 >> 1) & 3);
    const int aOff = (wm * 16 + l15) * 64 + slot * 16;   // + m*2048
    const int bOff = (wn * 16 + l15) * 64 + slot * 16;   // + n*4096

    i32x4 acc[8][4];
    #pragma unroll
    for (int m = 0; m < 8; ++m)
        #pragma unroll
        for (int n = 0; n < 4; ++n) acc[m][n] = (i32x4){0, 0, 0, 0};

    i32x4 arA[8], brA[4], arB[8], brB[4];

    auto readFragsS = [&](int s, i32x4 (&ar)[8], i32x4 (&br)[4]) {
        const int8_t* Ab = As + s * BUF;
        const int8_t* Bb = Bs + s * BUF;
        #pragma unroll
        for (int m = 0; m < 8; ++m) ar[m] = *(const i32x4*)(Ab + m * 2048 + aOff);
        #pragma unroll
        for (int n = 0; n < 4; ++n) br[n] = *(const i32x4*)(Bb + n * 4096 + bOff);
    };

    // ---- prologue: stage tiles 0..3; drain 0,1 (vmcnt(8)); barrier; frags(0) ----
    stageAB(0, 0); stageAB(1, 1); stageAB(2, 2); stageAB(3, 3);
    asm volatile("s_waitcnt vmcnt(8)" ::: "memory");
    __builtin_amdgcn_s_barrier();
    __builtin_amdgcn_sched_barrier(0);
    readFragsS(0, arA, brA);

    int sn = 1;   // ring slot of tile t+1 (reads)
    int ss = 4;   // ring slot of tile t+4 (stage)

    auto body = [&](int t, i32x4 (&arc)[8], i32x4 (&brc)[4],
                           i32x4 (&arn)[8], i32x4 (&brn)[4]) {
        // free-form region: compiler interleaves reads / stage / MFMAs
        if (t + 1 < NT) readFragsS(sn, arn, brn);
        if (t + 4 < NT) stageAB(t + 4, ss);

        __builtin_amdgcn_s_setprio(1);
        #pragma unroll
        for (int m = 0; m < 8; ++m)
            #pragma unroll
            for (int n = 0; n < 4; ++n)
                acc[m][n] = __builtin_amdgcn_mfma_i32_16x16x64_i8(arc[m], brc[n], acc[m][n], 0, 0, 0);
        __builtin_amdgcn_s_setprio(0);

        // ---- tile boundary guard block ----
        asm volatile("s_waitcnt lgkmcnt(12)" ::: "memory");  // all reads < t+1 done
        __builtin_amdgcn_sched_barrier(0);
        if (t <= NT - 5)      { asm volatile("s_waitcnt vmcnt(8)" ::: "memory"); }
        else if (t == NT - 4) { asm volatile("s_waitcnt vmcnt(4)" ::: "memory"); }
        else                  { asm volatile("s_waitcnt vmcnt(0)" ::: "memory"); }
        __builtin_amdgcn_s_barrier();
        __builtin_amdgcn_sched_barrier(0);

        sn = (sn == NRING - 1) ? 0 : sn + 1;
        ss = (ss == NRING - 1) ? 0 : ss + 1;
    };

    for (int t = 0; t < NT; t += 2) {
        body(t,     arA, brA, arB, brB);
        body(t + 1, arB, brB, arA, brA);
    }

    // ---- epilogue: out = acc * sinv[row] + bias[col] ----
    // C/D layout (dtype-independent, m121-128): col=lane&15, row=(lane>>4)*4+reg
    int   cols[4];
    float bv[4];
    #pragma unroll
    for (int n = 0; n < 4; ++n) {
        cols[n] = (int)bcol + n * 64 + wn * 16 + l15;
        bv[n] = bias[cols[n]];
    }
    #pragma unroll
    for (int m = 0; m < 8; ++m) {
        const size_t row0 = (size_t)brow + m * 32 + wm * 16 + l4 * 4;
        float s0 = sinv[row0], s1 = sinv[row0 + 1], s2 = sinv[row0 + 2], s3 = sinv[row0 + 3];
        #pragma unroll
        for (int n = 0; n < 4; ++n) {
            out[(row0 + 0) * N_DIM + cols[n]] = (float)acc[m][n][0] * s0 + bv[n];
            out[(row0 + 1) * N_DIM + cols[n]] = (float)acc[m][n][1] * s1 + bv[n];
            out[(row0 + 2) * N_DIM + cols[n]] = (float)acc[m][n][2] * s2 + bv[n];
            out[(row0 + 3) * N_DIM + cols[n]] = (float)acc[m][n][3] * s3 + bv[n];
        }
    }
}

// ---------- fallback (only if workspace too small): correct but slow ----------

__global__ void naive_kernel(const float* __restrict__ x, const float* __restrict__ w,
                             const float* __restrict__ bias, float* __restrict__ out) {
    long long o = (long long)blockIdx.x * blockDim.x + threadIdx.x;
    if (o >= (long long)M_DIM * N_DIM) return;
    int row = (int)(o / N_DIM), col = (int)(o % N_DIM);
    float s = 0.0f;
    const float* xr = x + (size_t)row * K_DIM;
    const float* wr = w + (size_t)col * K_DIM;
    for (int k = 0; k < K_DIM; ++k) {
        float wv = wr[k];
        s += (wv > 0.0f) ? xr[k] : ((wv < 0.0f) ? -xr[k] : 0.0f);
    }
    out[o] = s + bias[col];
}

// ---------- launch ----------

extern "C" void kernel_launch(void* const* d_in, const int* in_sizes, int n_in,
                              void* d_out, int out_size, void* d_ws, size_t ws_size,
                              hipStream_t stream) {
    const float* x    = (const float*)d_in[0];
    const float* w    = (const float*)d_in[1];
    const float* bias = (const float*)d_in[2];
    float* out        = (float*)d_out;

    const size_t xq_bytes = (size_t)M_DIM * K_DIM;        // 33.6 MB
    const size_t wq_bytes = (size_t)N_DIM * K_DIM;        // 45.1 MB
    const size_t si_bytes = (size_t)M_DIM * sizeof(float);

    if (ws_size >= xq_bytes + wq_bytes + si_bytes) {
        int8_t* xq   = (int8_t*)d_ws;
        int8_t* wq   = (int8_t*)((char*)d_ws + xq_bytes);
        float*  sinv = (float*)((char*)d_ws + xq_bytes + wq_bytes);

        quant_x_kernel<<<M_DIM / 4, 256, 0, stream>>>(x, xq, sinv);
        const long long n16 = ((long long)N_DIM * K_DIM) / 16;
        sign_w_kernel<<<2048, 256, 0, stream>>>(w, wq, n16);

        const int lds_bytes = NRING * 2 * BUF;   // 163840
        hipFuncSetAttribute(reinterpret_cast<const void*>(ternary_gemm_i8),
                            hipFuncAttributeMaxDynamicSharedMemorySize, lds_bytes);
        ternary_gemm_i8<<<NWG, 512, lds_bytes, stream>>>(xq, wq, bias, sinv, out);
    } else {
        const long long total = (long long)M_DIM * N_DIM;
        naive_kernel<<<(int)((total + 255) / 256), 256, 0, stream>>>(x, w, bias, out);
    }
}

// Round 10
// 476.295 us; speedup vs baseline: 1.1989x; 1.0065x over previous
//
#include <hip/hip_runtime.h>
#include <stdint.h>

#define M_DIM 8192
#define N_DIM 11008
#define K_DIM 4096

#define BM 256
#define BN 256
#define BK 64                    // i8: 64 B per row per tile
#define NT (K_DIM / BK)          // 64 K-tiles
#define GRID_M (M_DIM / BM)      // 32
#define GRID_N (N_DIM / BN)      // 43
#define NWG (GRID_M * GRID_N)    // 1376 (divisible by 8)

#define BUF (BM * BK)            // 16384 B per tile-buffer per matrix
#define NRING 5                  // ring-5: LDS = 5*2*16384 = 163840 B (160 KiB)

typedef int i32x4 __attribute__((ext_vector_type(4)));

__device__ __forceinline__ void gload16(const int8_t* src, int8_t* dst) {
    __builtin_amdgcn_global_load_lds(
        (const __attribute__((address_space(1))) uint32_t*)src,
        (__attribute__((address_space(3))) uint32_t*)dst, 16, 0, 0);
}

// ---------- pre-pass 1: per-row (token) absmax quant of x -> i8 + inv scale ----------

__global__ __launch_bounds__(256) void quant_x_kernel(
    const float* __restrict__ x, int8_t* __restrict__ xq, float* __restrict__ sinv)
{
    const int wave = blockIdx.x * 4 + (threadIdx.x >> 6);
    const int lane = threadIdx.x & 63;
    const float* row = x + (size_t)wave * K_DIM;

    float4 v[16];
    float mx = 0.0f;
    #pragma unroll
    for (int j = 0; j < 16; ++j) {
        v[j] = *(const float4*)(row + (j * 64 + lane) * 4);
        mx = fmaxf(mx, fmaxf(fmaxf(fabsf(v[j].x), fabsf(v[j].y)),
                             fmaxf(fabsf(v[j].z), fabsf(v[j].w))));
    }
    #pragma unroll
    for (int off = 32; off > 0; off >>= 1)
        mx = fmaxf(mx, __shfl_xor(mx, off));
    if (mx < 1e-30f) mx = 1e-30f;
    const float s = 127.0f / mx;

    int8_t* orow = xq + (size_t)wave * K_DIM;
    #pragma unroll
    for (int j = 0; j < 16; ++j) {
        int a = (int)__builtin_rintf(v[j].x * s);
        int b = (int)__builtin_rintf(v[j].y * s);
        int c = (int)__builtin_rintf(v[j].z * s);
        int d = (int)__builtin_rintf(v[j].w * s);
        uint32_t p = (uint32_t)(a & 0xFF) | ((uint32_t)(b & 0xFF) << 8) |
                     ((uint32_t)(c & 0xFF) << 16) | ((uint32_t)(d & 0xFF) << 24);
        *(uint32_t*)(orow + (j * 64 + lane) * 4) = p;
    }
    if (lane == 0) sinv[wave] = mx / 127.0f;
}

// ---------- pre-pass 2: f32 w -> sign(w) in i8 (exact {-1,0,+1}) ----------

__global__ __launch_bounds__(256) void sign_w_kernel(
    const float* __restrict__ w, int8_t* __restrict__ wq, long long n16)
{
    long long i = (long long)blockIdx.x * blockDim.x + threadIdx.x;
    const long long stride = (long long)gridDim.x * blockDim.x;
    for (; i < n16; i += stride) {
        const float* src = w + i * 16;
        uint32_t pk[4];
        #pragma unroll
        for (int q = 0; q < 4; ++q) {
            float4 f = *(const float4*)(src + q * 4);
            int a = (f.x > 0.f) ? 1 : ((f.x < 0.f) ? -1 : 0);
            int b = (f.y > 0.f) ? 1 : ((f.y < 0.f) ? -1 : 0);
            int c = (f.z > 0.f) ? 1 : ((f.z < 0.f) ? -1 : 0);
            int d = (f.w > 0.f) ? 1 : ((f.w < 0.f) ? -1 : 0);
            pk[q] = (uint32_t)(a & 0xFF) | ((uint32_t)(b & 0xFF) << 8) |
                    ((uint32_t)(c & 0xFF) << 16) | ((uint32_t)(d & 0xFF) << 24);
        }
        *(i32x4*)(wq + i * 16) = (i32x4){(int)pk[0], (int)pk[1], (int)pk[2], (int)pk[3]};
    }
}

// ---------- main GEMM (i8): 256x256, BK=64, 8 waves, RING-5 LDS (160 KiB),
// FORCED GROUP INTERLEAVE (r9 post-mortem): r8 (all-pinned) and r9 (all-free)
// both measured exact DS+MFMA serial sum (2590 cy/tile) -> a conservative
// compiler lgkmcnt(0) before the MFMA cluster (cross-iteration frag-set dep it
// can't count) drains the 12 just-issued reads each tile. Fix: 4 fenced groups
// per body, each {8 MFMA(t); 3 ds_reads(t+1); [2 stage gloads]}. A worst-case
// lgkmcnt(0) before an MFMA group now only waits on reads issued >=1 group ago
// (~288 cy of CU DS-pipe vs ~326 cy of preceding MFMA group -> drained, free).
// MFMA-first/reads-after inside each group maximizes drain slack.
//
// Boundary audit: NO lgkm wait needed. reads(t) are consumed by MFMA(t) before
// the boundary (issue requires completion); the next write to slot(t) is
// stage(t+5) in body(t+1), one barrier later. vmcnt ladder unchanged from r9:
// at boundary(t) outstanding = {stage(t+3), stage(t+4)} = 8 -> vmcnt(8)
// certifies stage(t+2) landed (tile t+2 needed two bodies later; tile t+1 was
// certified at boundary(t-1)). Tail: t==NT-4 -> vmcnt(4); else vmcnt(0).

__global__ __launch_bounds__(512, 2) void ternary_gemm_i8(
    const int8_t* __restrict__ A, const int8_t* __restrict__ B,
    const float* __restrict__ bias, const float* __restrict__ sinv,
    float* __restrict__ out)
{
    extern __shared__ int8_t lds[];
    int8_t* As = lds;                   // [NRING][BUF]
    int8_t* Bs = lds + NRING * BUF;     // [NRING][BUF]

    const int tid  = threadIdx.x;
    const int lane = tid & 63;
    const int wid  = tid >> 6;        // 0..7
    const int wm   = wid >> 2;        // 0..1
    const int wn   = wid & 3;         // 0..3
    const int l15  = lane & 15;
    const int l4   = lane >> 4;       // 0..3

    // T1: bijective XCD swizzle (NWG % 8 == 0), bn-minor for A-panel L2 reuse
    const int bid = blockIdx.x;
    const int swz = (bid & 7) * (NWG / 8) + (bid >> 3);
    const int bm  = swz / GRID_N;
    const int bn  = swz % GRID_N;
    const long brow = (long)bm * BM;
    const long bcol = (long)bn * BN;

    // ---- staging addressing (r6-verified): inst r covers rows r*128+(tid>>2),
    // 16B-slot tid&3; LDS dest linear (byte = r*8192 + tid*16); global src
    // slot inverse-swizzled: (tid&3) ^ ((tid>>3)&3) ----
    const int rowt = tid >> 2;                        // 0..127
    const int ssrc = (tid & 3) ^ ((tid >> 3) & 3);
    const int8_t* pA = A + (size_t)(brow + rowt) * K_DIM + ssrc * 16;
    const int8_t* pB = B + (size_t)(bcol + rowt) * K_DIM + ssrc * 16;

    auto stageA2 = [&](int t, int bslot) {
        #pragma unroll
        for (int r = 0; r < 2; ++r)
            gload16(pA + (size_t)r * 128 * K_DIM + (size_t)t * BK,
                    As + bslot * BUF + r * 8192 + wid * 1024 + (lane << 4));
    };
    auto stageB2 = [&](int t, int bslot) {
        #pragma unroll
        for (int r = 0; r < 2; ++r)
            gload16(pB + (size_t)r * 128 * K_DIM + (size_t)t * BK,
                    Bs + bslot * BUF + r * 8192 + wid * 1024 + (lane << 4));
    };

    // ---- fragment read addressing (r6-verified swizzle) ----
    const int slot = l4 ^ ((l15 >> 1) & 3);
    const int aOff = (wm * 16 + l15) * 64 + slot * 16;   // + m*2048
    const int bOff = (wn * 16 + l15) * 64 + slot * 16;   // + n*4096

    i32x4 acc[8][4];
    #pragma unroll
    for (int m = 0; m < 8; ++m)
        #pragma unroll
        for (int n = 0; n < 4; ++n) acc[m][n] = (i32x4){0, 0, 0, 0};

    i32x4 arA[8], brA[4], arB[8], brB[4];

    // ---- prologue: stage tiles 0..3; drain 0,1 (vmcnt(8)); barrier; frags(0) ----
    stageA2(0, 0); stageB2(0, 0);
    stageA2(1, 1); stageB2(1, 1);
    stageA2(2, 2); stageB2(2, 2);
    stageA2(3, 3); stageB2(3, 3);
    asm volatile("s_waitcnt vmcnt(8)" ::: "memory");
    __builtin_amdgcn_s_barrier();
    __builtin_amdgcn_sched_barrier(0);
    {
        const int8_t* Ab = As;            // slot 0
        const int8_t* Bb = Bs;
        #pragma unroll
        for (int m = 0; m < 8; ++m) arA[m] = *(const i32x4*)(Ab + m * 2048 + aOff);
        #pragma unroll
        for (int n = 0; n < 4; ++n) brA[n] = *(const i32x4*)(Bb + n * 4096 + bOff);
    }
    __builtin_amdgcn_sched_barrier(0);

    int sn = 1;   // ring slot of tile t+1 (reads)
    int ss = 4;   // ring slot of tile t+4 (stage)

    auto body = [&](int t, i32x4 (&arc)[8], i32x4 (&brc)[4],
                           i32x4 (&arn)[8], i32x4 (&brn)[4]) {
        const int8_t* An = As + sn * BUF;
        const int8_t* Bn = Bs + sn * BUF;
        const bool rd = (t + 1 < NT);
        const bool st = (t + 4 < NT);

        // ---- G0: MFMA m0,m1 ; reads ar[0..2] ----
        __builtin_amdgcn_s_setprio(1);
        #pragma unroll
        for (int m = 0; m < 2; ++m)
            #pragma unroll
            for (int n = 0; n < 4; ++n)
                acc[m][n] = __builtin_amdgcn_mfma_i32_16x16x64_i8(arc[m], brc[n], acc[m][n], 0, 0, 0);
        __builtin_amdgcn_s_setprio(0);
        if (rd) {
            arn[0] = *(const i32x4*)(An + 0 * 2048 + aOff);
            arn[1] = *(const i32x4*)(An + 1 * 2048 + aOff);
            arn[2] = *(const i32x4*)(An + 2 * 2048 + aOff);
        }
        __builtin_amdgcn_sched_barrier(0);

        // ---- G1: MFMA m2,m3 ; reads ar[3..5] ----
        __builtin_amdgcn_s_setprio(1);
        #pragma unroll
        for (int m = 2; m < 4; ++m)
            #pragma unroll
            for (int n = 0; n < 4; ++n)
                acc[m][n] = __builtin_amdgcn_mfma_i32_16x16x64_i8(arc[m], brc[n], acc[m][n], 0, 0, 0);
        __builtin_amdgcn_s_setprio(0);
        if (rd) {
            arn[3] = *(const i32x4*)(An + 3 * 2048 + aOff);
            arn[4] = *(const i32x4*)(An + 4 * 2048 + aOff);
            arn[5] = *(const i32x4*)(An + 5 * 2048 + aOff);
        }
        __builtin_amdgcn_sched_barrier(0);

        // ---- G2: MFMA m4,m5 ; reads ar[6,7], br[0] ; stage A(t+4) ----
        __builtin_amdgcn_s_setprio(1);
        #pragma unroll
        for (int m = 4; m < 6; ++m)
            #pragma unroll
            for (int n = 0; n < 4; ++n)
                acc[m][n] = __builtin_amdgcn_mfma_i32_16x16x64_i8(arc[m], brc[n], acc[m][n], 0, 0, 0);
        __builtin_amdgcn_s_setprio(0);
        if (rd) {
            arn[6] = *(const i32x4*)(An + 6 * 2048 + aOff);
            arn[7] = *(const i32x4*)(An + 7 * 2048 + aOff);
            brn[0] = *(const i32x4*)(Bn + 0 * 4096 + bOff);
        }
        if (st) stageA2(t + 4, ss);
        __builtin_amdgcn_sched_barrier(0);

        // ---- G3: MFMA m6,m7 ; reads br[1..3] ; stage B(t+4) ----
        __builtin_amdgcn_s_setprio(1);
        #pragma unroll
        for (int m = 6; m < 8; ++m)
            #pragma unroll
            for (int n = 0; n < 4; ++n)
                acc[m][n] = __builtin_amdgcn_mfma_i32_16x16x64_i8(arc[m], brc[n], acc[m][n], 0, 0, 0);
        __builtin_amdgcn_s_setprio(0);
        if (rd) {
            brn[1] = *(const i32x4*)(Bn + 1 * 4096 + bOff);
            brn[2] = *(const i32x4*)(Bn + 2 * 4096 + bOff);
            brn[3] = *(const i32x4*)(Bn + 3 * 4096 + bOff);
        }
        if (st) stageB2(t + 4, ss);
        __builtin_amdgcn_sched_barrier(0);

        // ---- tile boundary: vmcnt ladder + barrier (no lgkm wait needed) ----
        if (t <= NT - 5)      { asm volatile("s_waitcnt vmcnt(8)" ::: "memory"); }
        else if (t == NT - 4) { asm volatile("s_waitcnt vmcnt(4)" ::: "memory"); }
        else                  { asm volatile("s_waitcnt vmcnt(0)" ::: "memory"); }
        __builtin_amdgcn_s_barrier();
        __builtin_amdgcn_sched_barrier(0);

        sn = (sn == NRING - 1) ? 0 : sn + 1;
        ss = (ss == NRING - 1) ? 0 : ss + 1;
    };

    for (int t = 0; t < NT; t += 2) {
        body(t,     arA, brA, arB, brB);
        body(t + 1, arB, brB, arA, brA);
    }

    // ---- epilogue: out = acc * sinv[row] + bias[col] ----
    // C/D layout (dtype-independent, m121-128): col=lane&15, row=(lane>>4)*4+reg
    int   cols[4];
    float bv[4];
    #pragma unroll
    for (int n = 0; n < 4; ++n) {
        cols[n] = (int)bcol + n * 64 + wn * 16 + l15;
        bv[n] = bias[cols[n]];
    }
    #pragma unroll
    for (int m = 0; m < 8; ++m) {
        const size_t row0 = (size_t)brow + m * 32 + wm * 16 + l4 * 4;
        float s0 = sinv[row0], s1 = sinv[row0 + 1], s2 = sinv[row0 + 2], s3 = sinv[row0 + 3];
        #pragma unroll
        for (int n = 0; n < 4; ++n) {
            out[(row0 + 0) * N_DIM + cols[n]] = (float)acc[m][n][0] * s0 + bv[n];
            out[(row0 + 1) * N_DIM + cols[n]] = (float)acc[m][n][1] * s1 + bv[n];
            out[(row0 + 2) * N_DIM + cols[n]] = (float)acc[m][n][2] * s2 + bv[n];
            out[(row0 + 3) * N_DIM + cols[n]] = (float)acc[m][n][3] * s3 + bv[n];
        }
    }
}

// ---------- fallback (only if workspace too small): correct but slow ----------

__global__ void naive_kernel(const float* __restrict__ x, const float* __restrict__ w,
                             const float* __restrict__ bias, float* __restrict__ out) {
    long long o = (long long)blockIdx.x * blockDim.x + threadIdx.x;
    if (o >= (long long)M_DIM * N_DIM) return;
    int row = (int)(o / N_DIM), col = (int)(o % N_DIM);
    float s = 0.0f;
    const float* xr = x + (size_t)row * K_DIM;
    const float* wr = w + (size_t)col * K_DIM;
    for (int k = 0; k < K_DIM; ++k) {
        float wv = wr[k];
        s += (wv > 0.0f) ? xr[k] : ((wv < 0.0f) ? -xr[k] : 0.0f);
    }
    out[o] = s + bias[col];
}

// ---------- launch ----------

extern "C" void kernel_launch(void* const* d_in, const int* in_sizes, int n_in,
                              void* d_out, int out_size, void* d_ws, size_t ws_size,
                              hipStream_t stream) {
    const float* x    = (const float*)d_in[0];
    const float* w    = (const float*)d_in[1];
    const float* bias = (const float*)d_in[2];
    float* out        = (float*)d_out;

    const size_t xq_bytes = (size_t)M_DIM * K_DIM;        // 33.6 MB
    const size_t wq_bytes = (size_t)N_DIM * K_DIM;        // 45.1 MB
    const size_t si_bytes = (size_t)M_DIM * sizeof(float);

    if (ws_size >= xq_bytes + wq_bytes + si_bytes) {
        int8_t* xq   = (int8_t*)d_ws;
        int8_t* wq   = (int8_t*)((char*)d_ws + xq_bytes);
        float*  sinv = (float*)((char*)d_ws + xq_bytes + wq_bytes);

        quant_x_kernel<<<M_DIM / 4, 256, 0, stream>>>(x, xq, sinv);
        const long long n16 = ((long long)N_DIM * K_DIM) / 16;
        sign_w_kernel<<<2048, 256, 0, stream>>>(w, wq, n16);

        const int lds_bytes = NRING * 2 * BUF;   // 163840
        hipFuncSetAttribute(reinterpret_cast<const void*>(ternary_gemm_i8),
                            hipFuncAttributeMaxDynamicSharedMemorySize, lds_bytes);
        ternary_gemm_i8<<<NWG, 512, lds_bytes, stream>>>(xq, wq, bias, sinv, out);
    } else {
        const long long total = (long long)M_DIM * N_DIM;
        naive_kernel<<<(int)((total + 255) / 256), 256, 0, stream>>>(x, w, bias, out);
    }
}

// Round 11
// 470.166 us; speedup vs baseline: 1.2145x; 1.0130x over previous
//
#include <hip/hip_runtime.h>
#include <stdint.h>

#define M_DIM 8192
#define N_DIM 11008
#define K_DIM 4096

#define BM 256
#define BN 256
#define BK 64                    // i8: 64 B per row per tile
#define NT (K_DIM / BK)          // 64 K-tiles
#define GRID_M (M_DIM / BM)      // 32
#define GRID_N (N_DIM / BN)      // 43
#define NWG (GRID_M * GRID_N)    // 1376 (divisible by 8)

#define BUF (BM * BK)            // 16384 B per tile-buffer per matrix
#define NRING 5                  // ring-5: LDS = 5*2*16384 = 163840 B (160 KiB)

typedef int i32x4 __attribute__((ext_vector_type(4)));

__device__ __forceinline__ void gload16(const int8_t* src, int8_t* dst) {
    __builtin_amdgcn_global_load_lds(
        (const __attribute__((address_space(1))) uint32_t*)src,
        (__attribute__((address_space(3))) uint32_t*)dst, 16, 0, 0);
}

// ---------- pre-pass 1: per-row (token) absmax quant of x -> i8 + inv scale ----------

__global__ __launch_bounds__(256) void quant_x_kernel(
    const float* __restrict__ x, int8_t* __restrict__ xq, float* __restrict__ sinv)
{
    const int wave = blockIdx.x * 4 + (threadIdx.x >> 6);
    const int lane = threadIdx.x & 63;
    const float* row = x + (size_t)wave * K_DIM;

    float4 v[16];
    float mx = 0.0f;
    #pragma unroll
    for (int j = 0; j < 16; ++j) {
        v[j] = *(const float4*)(row + (j * 64 + lane) * 4);
        mx = fmaxf(mx, fmaxf(fmaxf(fabsf(v[j].x), fabsf(v[j].y)),
                             fmaxf(fabsf(v[j].z), fabsf(v[j].w))));
    }
    #pragma unroll
    for (int off = 32; off > 0; off >>= 1)
        mx = fmaxf(mx, __shfl_xor(mx, off));
    if (mx < 1e-30f) mx = 1e-30f;
    const float s = 127.0f / mx;

    int8_t* orow = xq + (size_t)wave * K_DIM;
    #pragma unroll
    for (int j = 0; j < 16; ++j) {
        int a = (int)__builtin_rintf(v[j].x * s);
        int b = (int)__builtin_rintf(v[j].y * s);
        int c = (int)__builtin_rintf(v[j].z * s);
        int d = (int)__builtin_rintf(v[j].w * s);
        uint32_t p = (uint32_t)(a & 0xFF) | ((uint32_t)(b & 0xFF) << 8) |
                     ((uint32_t)(c & 0xFF) << 16) | ((uint32_t)(d & 0xFF) << 24);
        *(uint32_t*)(orow + (j * 64 + lane) * 4) = p;
    }
    if (lane == 0) sinv[wave] = mx / 127.0f;
}

// ---------- pre-pass 2: f32 w -> sign(w) in i8 (exact {-1,0,+1}) ----------

__global__ __launch_bounds__(256) void sign_w_kernel(
    const float* __restrict__ w, int8_t* __restrict__ wq, long long n16)
{
    long long i = (long long)blockIdx.x * blockDim.x + threadIdx.x;
    const long long stride = (long long)gridDim.x * blockDim.x;
    for (; i < n16; i += stride) {
        const float* src = w + i * 16;
        uint32_t pk[4];
        #pragma unroll
        for (int q = 0; q < 4; ++q) {
            float4 f = *(const float4*)(src + q * 4);
            int a = (f.x > 0.f) ? 1 : ((f.x < 0.f) ? -1 : 0);
            int b = (f.y > 0.f) ? 1 : ((f.y < 0.f) ? -1 : 0);
            int c = (f.z > 0.f) ? 1 : ((f.z < 0.f) ? -1 : 0);
            int d = (f.w > 0.f) ? 1 : ((f.w < 0.f) ? -1 : 0);
            pk[q] = (uint32_t)(a & 0xFF) | ((uint32_t)(b & 0xFF) << 8) |
                    ((uint32_t)(c & 0xFF) << 16) | ((uint32_t)(d & 0xFF) << 24);
        }
        *(i32x4*)(wq + i * 16) = (i32x4){(int)pk[0], (int)pk[1], (int)pk[2], (int)pk[3]};
    }
}

// ---------- main GEMM (i8): 256x256, BK=64, 8 waves, RING-5 LDS (160 KiB),
// group interleave + PRIORITY-ORDERED READS (r10 post-mortem):
// lgkmcnt drains IN ORDER, and r10 issued br[0..3] LAST while the next body's
// FIRST MFMA group consumes br[0..3] -> waiting for br[3] = waiting for all 12
// reads incl. ones issued right before the barrier -> exact DS+MFMA serial sum
// every tile. Fix: issue reads in next-tile consumption order:
//   G0: MFMA m0,m1 ; reads brn[0..3], arn[0]
//   G1: MFMA m2,m3 ; reads arn[1..3]
//   G2: MFMA m4,m5 ; reads arn[4,5] ; stage A(t+4)
//   G3: MFMA m6,m7 ; reads arn[6,7] ; stage B(t+4)
// Next-body waits: G0 needs ar[0] (5th-oldest, issued a full body ago);
// G1 needs ar[3] (2 groups ago); G2/G3 need reads issued exactly 1 body ago.
// Every lgkm wait now has >=2 groups (~650+ cy) of drain slack -> DS work
// hides under the MFMA pipe.
//
// Boundary: vmcnt ladder only (8/4/0; stage(t+2) certified for next tiles;
// no lgkm wait needed at boundary). Ring-5 RAW/WAR audit unchanged from r9.

__global__ __launch_bounds__(512, 2) void ternary_gemm_i8(
    const int8_t* __restrict__ A, const int8_t* __restrict__ B,
    const float* __restrict__ bias, const float* __restrict__ sinv,
    float* __restrict__ out)
{
    extern __shared__ int8_t lds[];
    int8_t* As = lds;                   // [NRING][BUF]
    int8_t* Bs = lds + NRING * BUF;     // [NRING][BUF]

    const int tid  = threadIdx.x;
    const int lane = tid & 63;
    const int wid  = tid >> 6;        // 0..7
    const int wm   = wid >> 2;        // 0..1
    const int wn   = wid & 3;         // 0..3
    const int l15  = lane & 15;
    const int l4   = lane >> 4;       // 0..3

    // T1: bijective XCD swizzle (NWG % 8 == 0), bn-minor for A-panel L2 reuse
    const int bid = blockIdx.x;
    const int swz = (bid & 7) * (NWG / 8) + (bid >> 3);
    const int bm  = swz / GRID_N;
    const int bn  = swz % GRID_N;
    const long brow = (long)bm * BM;
    const long bcol = (long)bn * BN;

    // ---- staging addressing (r6-verified): inst r covers rows r*128+(tid>>2),
    // 16B-slot tid&3; LDS dest linear (byte = r*8192 + tid*16); global src
    // slot inverse-swizzled: (tid&3) ^ ((tid>>3)&3) ----
    const int rowt = tid >> 2;                        // 0..127
    const int ssrc = (tid & 3) ^ ((tid >> 3) & 3);
    const int8_t* pA = A + (size_t)(brow + rowt) * K_DIM + ssrc * 16;
    const int8_t* pB = B + (size_t)(bcol + rowt) * K_DIM + ssrc * 16;

    auto stageA2 = [&](int t, int bslot) {
        #pragma unroll
        for (int r = 0; r < 2; ++r)
            gload16(pA + (size_t)r * 128 * K_DIM + (size_t)t * BK,
                    As + bslot * BUF + r * 8192 + wid * 1024 + (lane << 4));
    };
    auto stageB2 = [&](int t, int bslot) {
        #pragma unroll
        for (int r = 0; r < 2; ++r)
            gload16(pB + (size_t)r * 128 * K_DIM + (size_t)t * BK,
                    Bs + bslot * BUF + r * 8192 + wid * 1024 + (lane << 4));
    };

    // ---- fragment read addressing (r6-verified swizzle) ----
    const int slot = l4 ^ ((l15 >> 1) & 3);
    const int aOff = (wm * 16 + l15) * 64 + slot * 16;   // + m*2048
    const int bOff = (wn * 16 + l15) * 64 + slot * 16;   // + n*4096

    i32x4 acc[8][4];
    #pragma unroll
    for (int m = 0; m < 8; ++m)
        #pragma unroll
        for (int n = 0; n < 4; ++n) acc[m][n] = (i32x4){0, 0, 0, 0};

    i32x4 arA[8], brA[4], arB[8], brB[4];

    // ---- prologue: stage tiles 0..3; drain 0,1 (vmcnt(8)); barrier; frags(0) ----
    stageA2(0, 0); stageB2(0, 0);
    stageA2(1, 1); stageB2(1, 1);
    stageA2(2, 2); stageB2(2, 2);
    stageA2(3, 3); stageB2(3, 3);
    asm volatile("s_waitcnt vmcnt(8)" ::: "memory");
    __builtin_amdgcn_s_barrier();
    __builtin_amdgcn_sched_barrier(0);
    {
        const int8_t* Ab = As;            // slot 0
        const int8_t* Bb = Bs;
        #pragma unroll
        for (int n = 0; n < 4; ++n) brA[n] = *(const i32x4*)(Bb + n * 4096 + bOff);
        #pragma unroll
        for (int m = 0; m < 8; ++m) arA[m] = *(const i32x4*)(Ab + m * 2048 + aOff);
    }
    __builtin_amdgcn_sched_barrier(0);

    int sn = 1;   // ring slot of tile t+1 (reads)
    int ss = 4;   // ring slot of tile t+4 (stage)

    auto body = [&](int t, i32x4 (&arc)[8], i32x4 (&brc)[4],
                           i32x4 (&arn)[8], i32x4 (&brn)[4]) {
        const int8_t* An = As + sn * BUF;
        const int8_t* Bn = Bs + sn * BUF;
        const bool rd = (t + 1 < NT);
        const bool st = (t + 4 < NT);

        // ---- G0: MFMA m0,m1 ; reads brn[0..3], arn[0] ----
        __builtin_amdgcn_s_setprio(1);
        #pragma unroll
        for (int m = 0; m < 2; ++m)
            #pragma unroll
            for (int n = 0; n < 4; ++n)
                acc[m][n] = __builtin_amdgcn_mfma_i32_16x16x64_i8(arc[m], brc[n], acc[m][n], 0, 0, 0);
        __builtin_amdgcn_s_setprio(0);
        if (rd) {
            brn[0] = *(const i32x4*)(Bn + 0 * 4096 + bOff);
            brn[1] = *(const i32x4*)(Bn + 1 * 4096 + bOff);
            brn[2] = *(const i32x4*)(Bn + 2 * 4096 + bOff);
            brn[3] = *(const i32x4*)(Bn + 3 * 4096 + bOff);
            arn[0] = *(const i32x4*)(An + 0 * 2048 + aOff);
        }
        __builtin_amdgcn_sched_barrier(0);

        // ---- G1: MFMA m2,m3 ; reads arn[1..3] ----
        __builtin_amdgcn_s_setprio(1);
        #pragma unroll
        for (int m = 2; m < 4; ++m)
            #pragma unroll
            for (int n = 0; n < 4; ++n)
                acc[m][n] = __builtin_amdgcn_mfma_i32_16x16x64_i8(arc[m], brc[n], acc[m][n], 0, 0, 0);
        __builtin_amdgcn_s_setprio(0);
        if (rd) {
            arn[1] = *(const i32x4*)(An + 1 * 2048 + aOff);
            arn[2] = *(const i32x4*)(An + 2 * 2048 + aOff);
            arn[3] = *(const i32x4*)(An + 3 * 2048 + aOff);
        }
        __builtin_amdgcn_sched_barrier(0);

        // ---- G2: MFMA m4,m5 ; reads arn[4,5] ; stage A(t+4) ----
        __builtin_amdgcn_s_setprio(1);
        #pragma unroll
        for (int m = 4; m < 6; ++m)
            #pragma unroll
            for (int n = 0; n < 4; ++n)
                acc[m][n] = __builtin_amdgcn_mfma_i32_16x16x64_i8(arc[m], brc[n], acc[m][n], 0, 0, 0);
        __builtin_amdgcn_s_setprio(0);
        if (rd) {
            arn[4] = *(const i32x4*)(An + 4 * 2048 + aOff);
            arn[5] = *(const i32x4*)(An + 5 * 2048 + aOff);
        }
        if (st) stageA2(t + 4, ss);
        __builtin_amdgcn_sched_barrier(0);

        // ---- G3: MFMA m6,m7 ; reads arn[6,7] ; stage B(t+4) ----
        __builtin_amdgcn_s_setprio(1);
        #pragma unroll
        for (int m = 6; m < 8; ++m)
            #pragma unroll
            for (int n = 0; n < 4; ++n)
                acc[m][n] = __builtin_amdgcn_mfma_i32_16x16x64_i8(arc[m], brc[n], acc[m][n], 0, 0, 0);
        __builtin_amdgcn_s_setprio(0);
        if (rd) {
            arn[6] = *(const i32x4*)(An + 6 * 2048 + aOff);
            arn[7] = *(const i32x4*)(An + 7 * 2048 + aOff);
        }
        if (st) stageB2(t + 4, ss);
        __builtin_amdgcn_sched_barrier(0);

        // ---- tile boundary: vmcnt ladder + barrier (no lgkm wait needed) ----
        if (t <= NT - 5)      { asm volatile("s_waitcnt vmcnt(8)" ::: "memory"); }
        else if (t == NT - 4) { asm volatile("s_waitcnt vmcnt(4)" ::: "memory"); }
        else                  { asm volatile("s_waitcnt vmcnt(0)" ::: "memory"); }
        __builtin_amdgcn_s_barrier();
        __builtin_amdgcn_sched_barrier(0);

        sn = (sn == NRING - 1) ? 0 : sn + 1;
        ss = (ss == NRING - 1) ? 0 : ss + 1;
    };

    for (int t = 0; t < NT; t += 2) {
        body(t,     arA, brA, arB, brB);
        body(t + 1, arB, brB, arA, brA);
    }

    // ---- epilogue: out = acc * sinv[row] + bias[col] ----
    // C/D layout (dtype-independent, m121-128): col=lane&15, row=(lane>>4)*4+reg
    int   cols[4];
    float bv[4];
    #pragma unroll
    for (int n = 0; n < 4; ++n) {
        cols[n] = (int)bcol + n * 64 + wn * 16 + l15;
        bv[n] = bias[cols[n]];
    }
    #pragma unroll
    for (int m = 0; m < 8; ++m) {
        const size_t row0 = (size_t)brow + m * 32 + wm * 16 + l4 * 4;
        float s0 = sinv[row0], s1 = sinv[row0 + 1], s2 = sinv[row0 + 2], s3 = sinv[row0 + 3];
        #pragma unroll
        for (int n = 0; n < 4; ++n) {
            out[(row0 + 0) * N_DIM + cols[n]] = (float)acc[m][n][0] * s0 + bv[n];
            out[(row0 + 1) * N_DIM + cols[n]] = (float)acc[m][n][1] * s1 + bv[n];
            out[(row0 + 2) * N_DIM + cols[n]] = (float)acc[m][n][2] * s2 + bv[n];
            out[(row0 + 3) * N_DIM + cols[n]] = (float)acc[m][n][3] * s3 + bv[n];
        }
    }
}

// ---------- fallback (only if workspace too small): correct but slow ----------

__global__ void naive_kernel(const float* __restrict__ x, const float* __restrict__ w,
                             const float* __restrict__ bias, float* __restrict__ out) {
    long long o = (long long)blockIdx.x * blockDim.x + threadIdx.x;
    if (o >= (long long)M_DIM * N_DIM) return;
    int row = (int)(o / N_DIM), col = (int)(o % N_DIM);
    float s = 0.0f;
    const float* xr = x + (size_t)row * K_DIM;
    const float* wr = w + (size_t)col * K_DIM;
    for (int k = 0; k < K_DIM; ++k) {
        float wv = wr[k];
        s += (wv > 0.0f) ? xr[k] : ((wv < 0.0f) ? -xr[k] : 0.0f);
    }
    out[o] = s + bias[col];
}

// ---------- launch ----------

extern "C" void kernel_launch(void* const* d_in, const int* in_sizes, int n_in,
                              void* d_out, int out_size, void* d_ws, size_t ws_size,
                              hipStream_t stream) {
    const float* x    = (const float*)d_in[0];
    const float* w    = (const float*)d_in[1];
    const float* bias = (const float*)d_in[2];
    float* out        = (float*)d_out;

    const size_t xq_bytes = (size_t)M_DIM * K_DIM;        // 33.6 MB
    const size_t wq_bytes = (size_t)N_DIM * K_DIM;        // 45.1 MB
    const size_t si_bytes = (size_t)M_DIM * sizeof(float);

    if (ws_size >= xq_bytes + wq_bytes + si_bytes) {
        int8_t* xq   = (int8_t*)d_ws;
        int8_t* wq   = (int8_t*)((char*)d_ws + xq_bytes);
        float*  sinv = (float*)((char*)d_ws + xq_bytes + wq_bytes);

        quant_x_kernel<<<M_DIM / 4, 256, 0, stream>>>(x, xq, sinv);
        const long long n16 = ((long long)N_DIM * K_DIM) / 16;
        sign_w_kernel<<<2048, 256, 0, stream>>>(w, wq, n16);

        const int lds_bytes = NRING * 2 * BUF;   // 163840
        hipFuncSetAttribute(reinterpret_cast<const void*>(ternary_gemm_i8),
                            hipFuncAttributeMaxDynamicSharedMemorySize, lds_bytes);
        ternary_gemm_i8<<<NWG, 512, lds_bytes, stream>>>(xq, wq, bias, sinv, out);
    } else {
        const long long total = (long long)M_DIM * N_DIM;
        naive_kernel<<<(int)((total + 255) / 256), 256, 0, stream>>>(x, w, bias, out);
    }
}